// Round 5
// baseline (2647.246 us; speedup 1.0000x reference)
//
#include <hip/hip_runtime.h>

#define N_NODES   50000
#define N_EDGES   600000
#define HID       128
#define N_GRAPHS  128
#define N_CLASSES 5
#define POOL_CHUNK 128
#define SCAN_BLK  ((N_NODES + 255) / 256)   // 196

// --- degree (in-degree by dst, excluding self-loops) ---
__global__ void k_deg(const int* __restrict__ dst, int* __restrict__ ideg, int E) {
    int i = blockIdx.x * blockDim.x + threadIdx.x;
    if (i < E) atomicAdd(&ideg[dst[i]], 1);
}

// --- 3-phase hierarchical scan of ideg -> row_start[0..n] ---
// phase 1 also computes dis[i] = 1/sqrt(deg+1) and xs[i] = dis[i]*x[i] (float4, .w=0)
__global__ void k_scan_part(const int* __restrict__ ideg, int* __restrict__ bsum,
                            float* __restrict__ dis, const float* __restrict__ x,
                            float4* __restrict__ xs, int n) {
    __shared__ int s[256];
    int t = threadIdx.x;
    int i = blockIdx.x * 256 + t;
    int v = (i < n) ? ideg[i] : 0;
    if (i < n) {
        float dd = 1.0f / sqrtf((float)v + 1.0f);
        dis[i] = dd;
        float4 o;
        o.x = dd * x[i * 3 + 0];
        o.y = dd * x[i * 3 + 1];
        o.z = dd * x[i * 3 + 2];
        o.w = 0.f;
        xs[i] = o;
    }
    s[t] = v;
    __syncthreads();
    for (int off = 128; off > 0; off >>= 1) {
        if (t < off) s[t] += s[t + off];
        __syncthreads();
    }
    if (t == 0) bsum[blockIdx.x] = s[0];
}

__global__ void k_scan_bsum(const int* __restrict__ bsum, int* __restrict__ boff, int B) {
    __shared__ int s[256];
    int t = threadIdx.x;
    int v = (t < B) ? bsum[t] : 0;
    s[t] = v;
    __syncthreads();
    for (int off = 1; off < 256; off <<= 1) {
        int u = (t >= off) ? s[t - off] : 0;
        __syncthreads();
        s[t] += u;
        __syncthreads();
    }
    if (t < B) boff[t] = s[t] - v;
    if (t == 255) boff[B] = s[255];  // grand total
}

__global__ void k_scan_write(const int* __restrict__ ideg, const int* __restrict__ boff,
                             int* __restrict__ row_start, int n, int B) {
    __shared__ int s[256];
    int t = threadIdx.x;
    int i = blockIdx.x * 256 + t;
    int v = (i < n) ? ideg[i] : 0;
    s[t] = v;
    __syncthreads();
    for (int off = 1; off < 256; off <<= 1) {
        int u = (t >= off) ? s[t - off] : 0;
        __syncthreads();
        s[t] += u;
        __syncthreads();
    }
    if (i < n) row_start[i] = boff[blockIdx.x] + s[t] - v;
    if (blockIdx.x == 0 && t == 0) row_start[n] = boff[B];
}

// --- CSR fill: col[] holds src of each incoming edge, grouped by dst ---
__global__ void k_fill(const int* __restrict__ src, const int* __restrict__ dst,
                       const int* __restrict__ row_start, int* __restrict__ cursor,
                       int* __restrict__ col, int E) {
    int i = blockIdx.x * blockDim.x + threadIdx.x;
    if (i < E) {
        int d = dst[i];
        int pos = atomicAdd(&cursor[d], 1);
        col[row_start[d] + pos] = src[i];
    }
}

// --- graph offsets via binary search on sorted batch ---
__global__ void k_goff(const int* __restrict__ batch, int* __restrict__ goff,
                       int* __restrict__ gcnt, int n) {
    __shared__ int s[N_GRAPHS + 1];
    int t = threadIdx.x;
    if (t <= N_GRAPHS) {
        int lo = 0, hi = n;
        while (lo < hi) {
            int mid = (lo + hi) >> 1;
            if (batch[mid] < t) lo = mid + 1; else hi = mid;
        }
        s[t] = lo;
        if (t < N_GRAPHS) goff[t] = lo;
    }
    __syncthreads();
    if (t < N_GRAPHS) gcnt[t] = s[t + 1] - s[t];
}

// --- layer-1 aggregation in 3-dim feature space: a[d] = dis_d*(xs[d] + sum_{s in N(d)} xs[s])
// S(xW) = (Sx)W: aggregate first in 3-dim space (800 KB L2-resident table).
__global__ __launch_bounds__(256) void k_agg3(const float4* __restrict__ xs,
                                              const float* __restrict__ dis,
                                              const int* __restrict__ row_start,
                                              const int* __restrict__ col,
                                              float* __restrict__ a) {
    int g = threadIdx.x >> 2;      // 64 dst-groups per block
    int f = threadIdx.x & 3;       // feature component (3 = pad)
    int d = blockIdx.x * 64 + g;
    if (d >= N_NODES) return;
    const float* xsf = (const float*)xs;
    int j0 = row_start[d], j1 = row_start[d + 1];
    float a0 = xsf[(size_t)d * 4 + f];   // self (lane 3 reads the 0 pad)
    float a1 = 0.f, a2 = 0.f, a3 = 0.f;
    int j = j0;
    for (; j + 3 < j1; j += 4) {
        int s0 = col[j], s1 = col[j + 1], s2 = col[j + 2], s3 = col[j + 3];
        a0 += xsf[(size_t)s0 * 4 + f];
        a1 += xsf[(size_t)s1 * 4 + f];
        a2 += xsf[(size_t)s2 * 4 + f];
        a3 += xsf[(size_t)s3 * 4 + f];
    }
    for (; j < j1; ++j)
        a0 += xsf[(size_t)col[j] * 4 + f];
    a[(size_t)d * 4 + f] = dis[d] * ((a0 + a1) + (a2 + a3));
}

// --- layer-1 GEMM on aggregated 3-dim input: h1[i,:] = relu( (a@W1)[i,:] + b1 ) ---
__global__ void k_gemm_l1(const float4* __restrict__ a, const float* __restrict__ W,
                          const float* __restrict__ bias, float* __restrict__ out, int n) {
    int idx = blockIdx.x * blockDim.x + threadIdx.x;  // n*32 threads, 4 cols each
    if (idx >= n * 32) return;
    int row = idx >> 5, c4 = (idx & 31) * 4;
    float4 av = a[row];
    float4 w0 = *(const float4*)&W[0 * HID + c4];
    float4 w1 = *(const float4*)&W[1 * HID + c4];
    float4 w2 = *(const float4*)&W[2 * HID + c4];
    float4 bv = *(const float4*)&bias[c4];
    float4 o;
    o.x = fmaxf(fmaf(av.z, w2.x, fmaf(av.y, w1.x, fmaf(av.x, w0.x, bv.x))), 0.f);
    o.y = fmaxf(fmaf(av.z, w2.y, fmaf(av.y, w1.y, fmaf(av.x, w0.y, bv.y))), 0.f);
    o.z = fmaxf(fmaf(av.z, w2.z, fmaf(av.y, w1.z, fmaf(av.x, w0.z, bv.z))), 0.f);
    o.w = fmaxf(fmaf(av.z, w2.w, fmaf(av.y, w1.w, fmaf(av.x, w0.w, bv.w))), 0.f);
    *(float4*)&out[(size_t)row * HID + c4] = o;
}

// --- 128-row GEMM: out = dis[:,None] * (h @ W), single barrier, PIPELINED.
// 512 threads/block, 128 rows/block, micro-tile 8 rows x 4 cols per thread.
// Full 128x128 W (64 KB) in LDS; K-loop split into K=4 halves with named
// register double-buffer a[8]/b[8] (static indexing only): prefetch next
// 4-k slice of h while FMA-ing the current -> global-load latency hides
// under 256 cyc of FMA (round-4 counters: VALUBusy 26%, FETCH 13MB ->
// latency-bound, loads and FMAs never overlapped).
// VGPR budget: acc 32 + a/b 64 + 8 ptrs 16 + misc ~= 126 <= 128 cap.
__global__ __launch_bounds__(512, 4) void k_gemm128(const float* __restrict__ h,
                                                    const float* __restrict__ W,
                                                    const float* __restrict__ dis,
                                                    float* __restrict__ out, int n) {
    __shared__ float Ws[HID * HID];   // 64 KB
    int t  = threadIdx.x;
    int tc = t & 31;        // col group: cols 4*tc .. 4*tc+3
    int tr = t >> 5;        // row group 0..15: rows row0 .. row0+7
    int row0 = blockIdx.x * 128 + tr * 8;

    // stage all of W: 8 coalesced 512-thread stripes of float4
    {
        const float4* wg = (const float4*)W;
        float4* wsv = (float4*)Ws;
#pragma unroll
        for (int i = 0; i < 8; ++i)
            wsv[i * 512 + t] = wg[i * 512 + t];
    }

    // clamped per-row base pointers
    const float* hp[8];
#pragma unroll
    for (int r = 0; r < 8; ++r) {
        int row = row0 + r; if (row >= n) row = n - 1;
        hp[r] = h + (size_t)row * HID;
    }

    // preload k-slice 0 into A while W staging drains
    float4 ha[8], hb[8];
#pragma unroll
    for (int r = 0; r < 8; ++r) ha[r] = *(const float4*)(hp[r]);

    float acc[8][4];
#pragma unroll
    for (int r = 0; r < 8; ++r)
#pragma unroll
        for (int c = 0; c < 4; ++c) acc[r][c] = 0.f;

    __syncthreads();   // the only barrier

#pragma unroll
    for (int k0 = 0; k0 < HID; k0 += 8) {
        // prefetch B = slice k0+4 (always exists: HID multiple of 8)
#pragma unroll
        for (int r = 0; r < 8; ++r) hb[r] = *(const float4*)(hp[r] + k0 + 4);
        // FMA on A = slice k0..k0+3
#pragma unroll
        for (int kk = 0; kk < 4; ++kk) {
            float4 wv = *(const float4*)&Ws[(k0 + kk) * HID + tc * 4];
#pragma unroll
            for (int r = 0; r < 8; ++r) {
                float hv = kk == 0 ? ha[r].x : kk == 1 ? ha[r].y : kk == 2 ? ha[r].z : ha[r].w;
                acc[r][0] = fmaf(hv, wv.x, acc[r][0]);
                acc[r][1] = fmaf(hv, wv.y, acc[r][1]);
                acc[r][2] = fmaf(hv, wv.z, acc[r][2]);
                acc[r][3] = fmaf(hv, wv.w, acc[r][3]);
            }
        }
        // prefetch A = slice k0+8 (guarded)
        if (k0 + 8 < HID) {
#pragma unroll
            for (int r = 0; r < 8; ++r) ha[r] = *(const float4*)(hp[r] + k0 + 8);
        }
        // FMA on B = slice k0+4..k0+7
#pragma unroll
        for (int kk = 0; kk < 4; ++kk) {
            float4 wv = *(const float4*)&Ws[(k0 + 4 + kk) * HID + tc * 4];
#pragma unroll
            for (int r = 0; r < 8; ++r) {
                float hv = kk == 0 ? hb[r].x : kk == 1 ? hb[r].y : kk == 2 ? hb[r].z : hb[r].w;
                acc[r][0] = fmaf(hv, wv.x, acc[r][0]);
                acc[r][1] = fmaf(hv, wv.y, acc[r][1]);
                acc[r][2] = fmaf(hv, wv.z, acc[r][2]);
                acc[r][3] = fmaf(hv, wv.w, acc[r][3]);
            }
        }
    }

#pragma unroll
    for (int r = 0; r < 8; ++r) {
        int row = row0 + r;
        if (row < n) {
            float dd = dis[row];
            float4 o;
            o.x = dd * acc[r][0]; o.y = dd * acc[r][1];
            o.z = dd * acc[r][2]; o.w = dd * acc[r][3];
            *(float4*)&out[(size_t)row * HID + tc * 4] = o;
        }
    }
}

// --- aggregation on pre-scaled t: out[d] = relu( dis[d] * (t[d] + sum_{s in N(d)} t[s]) + b )
__global__ __launch_bounds__(256) void k_agg(const float* __restrict__ t,
                                             const float* __restrict__ dis,
                                             const int* __restrict__ row_start,
                                             const int* __restrict__ col,
                                             const float* __restrict__ bias,
                                             float* __restrict__ out) {
    int lane = threadIdx.x & 63;
    int wid  = threadIdx.x >> 6;
    int d = blockIdx.x * 4 + wid;
    if (d >= N_NODES) return;
    const float2* t2 = (const float2*)t;
    float2 bv = ((const float2*)bias)[lane];
    float dd = dis[d];
    int j0 = row_start[d], j1 = row_start[d + 1];
    float2 self = t2[(size_t)d * 64 + lane];
    float ax0 = self.x, ay0 = self.y;
    float ax1 = 0.f, ay1 = 0.f, ax2 = 0.f, ay2 = 0.f, ax3 = 0.f, ay3 = 0.f;
    int j = j0;
    for (; j + 3 < j1; j += 4) {
        int s0 = col[j], s1 = col[j + 1], s2 = col[j + 2], s3 = col[j + 3];
        float2 v0 = t2[(size_t)s0 * 64 + lane];
        float2 v1 = t2[(size_t)s1 * 64 + lane];
        float2 v2 = t2[(size_t)s2 * 64 + lane];
        float2 v3 = t2[(size_t)s3 * 64 + lane];
        ax0 += v0.x; ay0 += v0.y;
        ax1 += v1.x; ay1 += v1.y;
        ax2 += v2.x; ay2 += v2.y;
        ax3 += v3.x; ay3 += v3.y;
    }
    for (; j < j1; ++j) {
        int s = col[j];
        float2 v = t2[(size_t)s * 64 + lane];
        ax0 += v.x; ay0 += v.y;
    }
    float sx = (ax0 + ax1) + (ax2 + ax3);
    float sy = (ay0 + ay1) + (ay2 + ay3);
    float2 o;
    o.x = fmaxf(fmaf(dd, sx, bv.x), 0.f);
    o.y = fmaxf(fmaf(dd, sy, bv.y), 0.f);
    ((float2*)out)[(size_t)d * 64 + lane] = o;
}

// --- node-parallel pool partial sums ---
__global__ void k_psum(const float* __restrict__ h, const int* __restrict__ batch,
                       float* __restrict__ fpsum, int n) {
    int i0 = blockIdx.x * POOL_CHUNK;
    int f = threadIdx.x;
    int end = min(i0 + POOL_CHUNK, n);
    int cur = batch[i0];
    float acc = 0.f;
    for (int i = i0; i < end; ++i) {
        int g = batch[i];
        if (g != cur) {
            atomicAdd(&fpsum[cur * HID + f], acc);
            acc = 0.f;
            cur = g;
        }
        acc += h[(size_t)i * HID + f];
    }
    atomicAdd(&fpsum[cur * HID + f], acc);
}

// --- final linear with mean folded in ---
__global__ void k_final(const float* __restrict__ fpsum, const int* __restrict__ gcnt,
                        const float* __restrict__ Wl, const float* __restrict__ bl,
                        float* __restrict__ out) {
    int idx = blockIdx.x * blockDim.x + threadIdx.x;
    if (idx >= N_GRAPHS * N_CLASSES) return;
    int g = idx / N_CLASSES, c = idx % N_CLASSES;
    float inv = 1.0f / (float)max(gcnt[g], 1);
    float acc = bl[c];
    for (int f = 0; f < HID; ++f)
        acc = fmaf(fpsum[g * HID + f] * inv, Wl[f * N_CLASSES + c], acc);
    out[idx] = acc;
}

extern "C" void kernel_launch(void* const* d_in, const int* in_sizes, int n_in,
                              void* d_out, int out_size, void* d_ws, size_t ws_size,
                              hipStream_t stream) {
    const float* x     = (const float*)d_in[0];
    const int*   ei    = (const int*)d_in[1];   // [2, E]: row0 = src, row1 = dst
    const int*   batch = (const int*)d_in[2];
    const float* W1 = (const float*)d_in[3];
    const float* b1 = (const float*)d_in[4];
    const float* W2 = (const float*)d_in[5];
    const float* b2 = (const float*)d_in[6];
    const float* W3 = (const float*)d_in[7];
    const float* b3 = (const float*)d_in[8];
    const float* Wl = (const float*)d_in[9];
    const float* bl = (const float*)d_in[10];
    float* out = (float*)d_out;

    const int N = N_NODES, E = N_EDGES;
    const int* srcp = ei;
    const int* dstp = ei + E;

    char* ws = (char*)d_ws;
    size_t off = 0;
    auto alloc = [&](size_t bytes) -> void* {
        void* p = ws + off;
        off += (bytes + 255) & ~(size_t)255;
        return p;
    };
    // zero-initialized region must be first & contiguous (ws is poisoned 0xAA each call)
    int*   ideg   = (int*)alloc((size_t)N * 4);
    int*   cursor = (int*)alloc((size_t)N * 4);
    float* fpsum  = (float*)alloc((size_t)N_GRAPHS * HID * 4);
    size_t zero_bytes = off;
    int*   gcnt  = (int*)alloc((size_t)N_GRAPHS * 4);
    float* dis   = (float*)alloc((size_t)N * 4);
    int*   rowst = (int*)alloc((size_t)(N + 1) * 4);
    int*   col   = (int*)alloc((size_t)E * 4);
    int*   goff  = (int*)alloc((size_t)N_GRAPHS * 4);
    int*   bsum  = (int*)alloc((size_t)SCAN_BLK * 4);
    int*   boff  = (int*)alloc((size_t)(SCAN_BLK + 1) * 4);
    float* bufA  = (float*)alloc((size_t)N * HID * 4);
    float* bufB  = (float*)alloc((size_t)N * HID * 4);
    float4* xs   = (float4*)alloc((size_t)N * 16);
    float*  aggx = (float*)alloc((size_t)N * 16);

    hipMemsetAsync(d_ws, 0, zero_bytes, stream);

    const int tpb = 256;
    k_deg<<<(E + tpb - 1) / tpb, tpb, 0, stream>>>(dstp, ideg, E);
    k_scan_part<<<SCAN_BLK, 256, 0, stream>>>(ideg, bsum, dis, x, xs, N);
    k_scan_bsum<<<1, 256, 0, stream>>>(bsum, boff, SCAN_BLK);
    k_scan_write<<<SCAN_BLK, 256, 0, stream>>>(ideg, boff, rowst, N, SCAN_BLK);
    k_fill<<<(E + tpb - 1) / tpb, tpb, 0, stream>>>(srcp, dstp, rowst, cursor, col, E);
    k_goff<<<1, 256, 0, stream>>>(batch, goff, gcnt, N);

    // layer 1: aggregate in 3-dim space, then GEMM (S(xW) = (Sx)W)
    k_agg3<<<(N + 63) / 64, 256, 0, stream>>>(xs, dis, rowst, col, aggx);
    k_gemm_l1<<<(N * 32 + tpb - 1) / tpb, tpb, 0, stream>>>((const float4*)aggx, W1, b1, bufB, N);
    // layer 2
    k_gemm128<<<(N + 127) / 128, 512, 0, stream>>>(bufB, W2, dis, bufA, N);
    k_agg<<<(N + 3) / 4, 256, 0, stream>>>(bufA, dis, rowst, col, b2, bufB);
    // layer 3
    k_gemm128<<<(N + 127) / 128, 512, 0, stream>>>(bufB, W3, dis, bufA, N);
    k_agg<<<(N + 3) / 4, 256, 0, stream>>>(bufA, dis, rowst, col, b3, bufB);
    // pool + classifier
    k_psum<<<(N + POOL_CHUNK - 1) / POOL_CHUNK, HID, 0, stream>>>(bufB, batch, fpsum, N);
    k_final<<<(N_GRAPHS * N_CLASSES + tpb - 1) / tpb, tpb, 0, stream>>>(fpsum, gcnt, Wl, bl, out);
}

// Round 6
// 426.799 us; speedup vs baseline: 6.2026x; 6.2026x over previous
//
#include <hip/hip_runtime.h>

#define N_NODES   50000
#define N_EDGES   600000
#define HID       128
#define N_GRAPHS  128
#define N_CLASSES 5
#define POOL_CHUNK 128
#define SCAN_BLK  ((N_NODES + 255) / 256)   // 196

// --- degree (in-degree by dst, excluding self-loops) ---
__global__ void k_deg(const int* __restrict__ dst, int* __restrict__ ideg, int E) {
    int i = blockIdx.x * blockDim.x + threadIdx.x;
    if (i < E) atomicAdd(&ideg[dst[i]], 1);
}

// --- 3-phase hierarchical scan of ideg -> row_start[0..n] ---
// phase 1 also computes dis[i] = 1/sqrt(deg+1) and xs[i] = dis[i]*x[i] (float4, .w=0)
__global__ void k_scan_part(const int* __restrict__ ideg, int* __restrict__ bsum,
                            float* __restrict__ dis, const float* __restrict__ x,
                            float4* __restrict__ xs, int n) {
    __shared__ int s[256];
    int t = threadIdx.x;
    int i = blockIdx.x * 256 + t;
    int v = (i < n) ? ideg[i] : 0;
    if (i < n) {
        float dd = 1.0f / sqrtf((float)v + 1.0f);
        dis[i] = dd;
        float4 o;
        o.x = dd * x[i * 3 + 0];
        o.y = dd * x[i * 3 + 1];
        o.z = dd * x[i * 3 + 2];
        o.w = 0.f;
        xs[i] = o;
    }
    s[t] = v;
    __syncthreads();
    for (int off = 128; off > 0; off >>= 1) {
        if (t < off) s[t] += s[t + off];
        __syncthreads();
    }
    if (t == 0) bsum[blockIdx.x] = s[0];
}

__global__ void k_scan_bsum(const int* __restrict__ bsum, int* __restrict__ boff, int B) {
    __shared__ int s[256];
    int t = threadIdx.x;
    int v = (t < B) ? bsum[t] : 0;
    s[t] = v;
    __syncthreads();
    for (int off = 1; off < 256; off <<= 1) {
        int u = (t >= off) ? s[t - off] : 0;
        __syncthreads();
        s[t] += u;
        __syncthreads();
    }
    if (t < B) boff[t] = s[t] - v;
    if (t == 255) boff[B] = s[255];  // grand total
}

__global__ void k_scan_write(const int* __restrict__ ideg, const int* __restrict__ boff,
                             int* __restrict__ row_start, int n, int B) {
    __shared__ int s[256];
    int t = threadIdx.x;
    int i = blockIdx.x * 256 + t;
    int v = (i < n) ? ideg[i] : 0;
    s[t] = v;
    __syncthreads();
    for (int off = 1; off < 256; off <<= 1) {
        int u = (t >= off) ? s[t - off] : 0;
        __syncthreads();
        s[t] += u;
        __syncthreads();
    }
    if (i < n) row_start[i] = boff[blockIdx.x] + s[t] - v;
    if (blockIdx.x == 0 && t == 0) row_start[n] = boff[B];
}

// --- CSR fill: col[] holds src of each incoming edge, grouped by dst ---
__global__ void k_fill(const int* __restrict__ src, const int* __restrict__ dst,
                       const int* __restrict__ row_start, int* __restrict__ cursor,
                       int* __restrict__ col, int E) {
    int i = blockIdx.x * blockDim.x + threadIdx.x;
    if (i < E) {
        int d = dst[i];
        int pos = atomicAdd(&cursor[d], 1);
        col[row_start[d] + pos] = src[i];
    }
}

// --- graph offsets via binary search on sorted batch ---
__global__ void k_goff(const int* __restrict__ batch, int* __restrict__ goff,
                       int* __restrict__ gcnt, int n) {
    __shared__ int s[N_GRAPHS + 1];
    int t = threadIdx.x;
    if (t <= N_GRAPHS) {
        int lo = 0, hi = n;
        while (lo < hi) {
            int mid = (lo + hi) >> 1;
            if (batch[mid] < t) lo = mid + 1; else hi = mid;
        }
        s[t] = lo;
        if (t < N_GRAPHS) goff[t] = lo;
    }
    __syncthreads();
    if (t < N_GRAPHS) gcnt[t] = s[t + 1] - s[t];
}

// --- layer-1 aggregation in 3-dim feature space: a[d] = dis_d*(xs[d] + sum_{s in N(d)} xs[s])
// S(xW) = (Sx)W: aggregate first in 3-dim space (800 KB L2-resident table).
__global__ __launch_bounds__(256) void k_agg3(const float4* __restrict__ xs,
                                              const float* __restrict__ dis,
                                              const int* __restrict__ row_start,
                                              const int* __restrict__ col,
                                              float* __restrict__ a) {
    int g = threadIdx.x >> 2;      // 64 dst-groups per block
    int f = threadIdx.x & 3;       // feature component (3 = pad)
    int d = blockIdx.x * 64 + g;
    if (d >= N_NODES) return;
    const float* xsf = (const float*)xs;
    int j0 = row_start[d], j1 = row_start[d + 1];
    float a0 = xsf[(size_t)d * 4 + f];   // self (lane 3 reads the 0 pad)
    float a1 = 0.f, a2 = 0.f, a3 = 0.f;
    int j = j0;
    for (; j + 3 < j1; j += 4) {
        int s0 = col[j], s1 = col[j + 1], s2 = col[j + 2], s3 = col[j + 3];
        a0 += xsf[(size_t)s0 * 4 + f];
        a1 += xsf[(size_t)s1 * 4 + f];
        a2 += xsf[(size_t)s2 * 4 + f];
        a3 += xsf[(size_t)s3 * 4 + f];
    }
    for (; j < j1; ++j)
        a0 += xsf[(size_t)col[j] * 4 + f];
    a[(size_t)d * 4 + f] = dis[d] * ((a0 + a1) + (a2 + a3));
}

// --- layer-1 GEMM on aggregated 3-dim input: h1[i,:] = relu( (a@W1)[i,:] + b1 ) ---
__global__ void k_gemm_l1(const float4* __restrict__ a, const float* __restrict__ W,
                          const float* __restrict__ bias, float* __restrict__ out, int n) {
    int idx = blockIdx.x * blockDim.x + threadIdx.x;  // n*32 threads, 4 cols each
    if (idx >= n * 32) return;
    int row = idx >> 5, c4 = (idx & 31) * 4;
    float4 av = a[row];
    float4 w0 = *(const float4*)&W[0 * HID + c4];
    float4 w1 = *(const float4*)&W[1 * HID + c4];
    float4 w2 = *(const float4*)&W[2 * HID + c4];
    float4 bv = *(const float4*)&bias[c4];
    float4 o;
    o.x = fmaxf(fmaf(av.z, w2.x, fmaf(av.y, w1.x, fmaf(av.x, w0.x, bv.x))), 0.f);
    o.y = fmaxf(fmaf(av.z, w2.y, fmaf(av.y, w1.y, fmaf(av.x, w0.y, bv.y))), 0.f);
    o.z = fmaxf(fmaf(av.z, w2.z, fmaf(av.y, w1.z, fmaf(av.x, w0.z, bv.z))), 0.f);
    o.w = fmaxf(fmaf(av.z, w2.w, fmaf(av.y, w1.w, fmaf(av.x, w0.w, bv.w))), 0.f);
    *(float4*)&out[(size_t)row * HID + c4] = o;
}

// --- 128-row GEMM: out = dis[:,None] * (h @ W).
// 512 threads/block, 128 rows/block, micro-tile 8 rows x 4 cols per thread.
// Full 128x128 W (64 KB) in LDS (staged once) + h k-slices staged via a
// double-buffered 128x8 LDS tile (2 x 4 KB): ONE global load per h element
// per block instead of the 32-way redundant per-thread broadcast loads
// (round-4: 256 vmem instrs/thread -> latency-bound, VALUBusy 26%).
// T14 split: prefetch load issued BEFORE the FMA phase, ds_write AFTER
// (FMA covers the HBM/L2 latency), one barrier per k-step.
// Register discipline (round-5 spill lesson): k0 loop NOT unrolled, single
// 8xfloat4 h-reg buffer reused for both k-halves, no pointer arrays.
__global__ __launch_bounds__(512, 4) void k_gemm128(const float* __restrict__ h,
                                                    const float* __restrict__ W,
                                                    const float* __restrict__ dis,
                                                    float* __restrict__ out, int n) {
    __shared__ float Ws[HID * HID];      // 64 KB
    __shared__ float Hs[2][128 * 8];     // 2 x 4 KB
    int t  = threadIdx.x;
    int tc = t & 31;        // col group: cols 4*tc .. 4*tc+3
    int tr = t >> 5;        // row group 0..15: rows row0 .. row0+7
    int row0 = blockIdx.x * 128 + tr * 8;

    // stage all of W: 8 coalesced 512-thread stripes of float4
    {
        const float4* wg = (const float4*)W;
        float4* wsv = (float4*)Ws;
#pragma unroll
        for (int i = 0; i < 8; ++i)
            wsv[i * 512 + t] = wg[i * 512 + t];
    }

    // h staging: threads 0..255 stage 128 rows x 8 k per step (row = t>>1, half = t&1)
    int srow = blockIdx.x * 128 + (t >> 1);
    if (srow >= n) srow = n - 1;                 // clamp; stores guarded below
    const float* hsrc = h + (size_t)srow * HID + (t & 1) * 4;
    int sidx = (t >> 1) * 8 + (t & 1) * 4;
    if (t < 256)
        *(float4*)&Hs[0][sidx] = *(const float4*)hsrc;

    float acc[8][4];
#pragma unroll
    for (int r = 0; r < 8; ++r)
#pragma unroll
        for (int c = 0; c < 4; ++c) acc[r][c] = 0.f;

    __syncthreads();

    int buf = 0;
    for (int k0 = 0; k0 < HID; k0 += 8) {       // NOT unrolled (VGPR cap)
        // T14 issue-early: next k-slice global->reg
        float4 pf;
        bool do_pf = (k0 + 8 < HID) && (t < 256);
        if (do_pf) pf = *(const float4*)(hsrc + k0 + 8);

        // h fragment for this step: 8 rows x 8 k from LDS (broadcast reads)
        float4 hv4[8];
#pragma unroll
        for (int r = 0; r < 8; ++r)
            hv4[r] = *(const float4*)&Hs[buf][(tr * 8 + r) * 8];
#pragma unroll
        for (int kk = 0; kk < 4; ++kk) {
            float4 wv = *(const float4*)&Ws[(k0 + kk) * HID + tc * 4];
#pragma unroll
            for (int r = 0; r < 8; ++r) {
                float hv = kk == 0 ? hv4[r].x : kk == 1 ? hv4[r].y : kk == 2 ? hv4[r].z : hv4[r].w;
                acc[r][0] = fmaf(hv, wv.x, acc[r][0]);
                acc[r][1] = fmaf(hv, wv.y, acc[r][1]);
                acc[r][2] = fmaf(hv, wv.z, acc[r][2]);
                acc[r][3] = fmaf(hv, wv.w, acc[r][3]);
            }
        }
#pragma unroll
        for (int r = 0; r < 8; ++r)
            hv4[r] = *(const float4*)&Hs[buf][(tr * 8 + r) * 8 + 4];
#pragma unroll
        for (int kk = 0; kk < 4; ++kk) {
            float4 wv = *(const float4*)&Ws[(k0 + 4 + kk) * HID + tc * 4];
#pragma unroll
            for (int r = 0; r < 8; ++r) {
                float hv = kk == 0 ? hv4[r].x : kk == 1 ? hv4[r].y : kk == 2 ? hv4[r].z : hv4[r].w;
                acc[r][0] = fmaf(hv, wv.x, acc[r][0]);
                acc[r][1] = fmaf(hv, wv.y, acc[r][1]);
                acc[r][2] = fmaf(hv, wv.z, acc[r][2]);
                acc[r][3] = fmaf(hv, wv.w, acc[r][3]);
            }
        }

        // T14 write-late: latency hidden under the FMAs above
        if (do_pf) *(float4*)&Hs[buf ^ 1][sidx] = pf;
        __syncthreads();
        buf ^= 1;
    }

#pragma unroll
    for (int r = 0; r < 8; ++r) {
        int row = row0 + r;
        if (row < n) {
            float dd = dis[row];
            float4 o;
            o.x = dd * acc[r][0]; o.y = dd * acc[r][1];
            o.z = dd * acc[r][2]; o.w = dd * acc[r][3];
            *(float4*)&out[(size_t)row * HID + tc * 4] = o;
        }
    }
}

// --- aggregation on pre-scaled t: out[d] = relu( dis[d] * (t[d] + sum_{s in N(d)} t[s]) + b )
__global__ __launch_bounds__(256) void k_agg(const float* __restrict__ t,
                                             const float* __restrict__ dis,
                                             const int* __restrict__ row_start,
                                             const int* __restrict__ col,
                                             const float* __restrict__ bias,
                                             float* __restrict__ out) {
    int lane = threadIdx.x & 63;
    int wid  = threadIdx.x >> 6;
    int d = blockIdx.x * 4 + wid;
    if (d >= N_NODES) return;
    const float2* t2 = (const float2*)t;
    float2 bv = ((const float2*)bias)[lane];
    float dd = dis[d];
    int j0 = row_start[d], j1 = row_start[d + 1];
    float2 self = t2[(size_t)d * 64 + lane];
    float ax0 = self.x, ay0 = self.y;
    float ax1 = 0.f, ay1 = 0.f, ax2 = 0.f, ay2 = 0.f, ax3 = 0.f, ay3 = 0.f;
    int j = j0;
    for (; j + 3 < j1; j += 4) {
        int s0 = col[j], s1 = col[j + 1], s2 = col[j + 2], s3 = col[j + 3];
        float2 v0 = t2[(size_t)s0 * 64 + lane];
        float2 v1 = t2[(size_t)s1 * 64 + lane];
        float2 v2 = t2[(size_t)s2 * 64 + lane];
        float2 v3 = t2[(size_t)s3 * 64 + lane];
        ax0 += v0.x; ay0 += v0.y;
        ax1 += v1.x; ay1 += v1.y;
        ax2 += v2.x; ay2 += v2.y;
        ax3 += v3.x; ay3 += v3.y;
    }
    for (; j < j1; ++j) {
        int s = col[j];
        float2 v = t2[(size_t)s * 64 + lane];
        ax0 += v.x; ay0 += v.y;
    }
    float sx = (ax0 + ax1) + (ax2 + ax3);
    float sy = (ay0 + ay1) + (ay2 + ay3);
    float2 o;
    o.x = fmaxf(fmaf(dd, sx, bv.x), 0.f);
    o.y = fmaxf(fmaf(dd, sy, bv.y), 0.f);
    ((float2*)out)[(size_t)d * 64 + lane] = o;
}

// --- node-parallel pool partial sums ---
__global__ void k_psum(const float* __restrict__ h, const int* __restrict__ batch,
                       float* __restrict__ fpsum, int n) {
    int i0 = blockIdx.x * POOL_CHUNK;
    int f = threadIdx.x;
    int end = min(i0 + POOL_CHUNK, n);
    int cur = batch[i0];
    float acc = 0.f;
    for (int i = i0; i < end; ++i) {
        int g = batch[i];
        if (g != cur) {
            atomicAdd(&fpsum[cur * HID + f], acc);
            acc = 0.f;
            cur = g;
        }
        acc += h[(size_t)i * HID + f];
    }
    atomicAdd(&fpsum[cur * HID + f], acc);
}

// --- final linear with mean folded in ---
__global__ void k_final(const float* __restrict__ fpsum, const int* __restrict__ gcnt,
                        const float* __restrict__ Wl, const float* __restrict__ bl,
                        float* __restrict__ out) {
    int idx = blockIdx.x * blockDim.x + threadIdx.x;
    if (idx >= N_GRAPHS * N_CLASSES) return;
    int g = idx / N_CLASSES, c = idx % N_CLASSES;
    float inv = 1.0f / (float)max(gcnt[g], 1);
    float acc = bl[c];
    for (int f = 0; f < HID; ++f)
        acc = fmaf(fpsum[g * HID + f] * inv, Wl[f * N_CLASSES + c], acc);
    out[idx] = acc;
}

extern "C" void kernel_launch(void* const* d_in, const int* in_sizes, int n_in,
                              void* d_out, int out_size, void* d_ws, size_t ws_size,
                              hipStream_t stream) {
    const float* x     = (const float*)d_in[0];
    const int*   ei    = (const int*)d_in[1];   // [2, E]: row0 = src, row1 = dst
    const int*   batch = (const int*)d_in[2];
    const float* W1 = (const float*)d_in[3];
    const float* b1 = (const float*)d_in[4];
    const float* W2 = (const float*)d_in[5];
    const float* b2 = (const float*)d_in[6];
    const float* W3 = (const float*)d_in[7];
    const float* b3 = (const float*)d_in[8];
    const float* Wl = (const float*)d_in[9];
    const float* bl = (const float*)d_in[10];
    float* out = (float*)d_out;

    const int N = N_NODES, E = N_EDGES;
    const int* srcp = ei;
    const int* dstp = ei + E;

    char* ws = (char*)d_ws;
    size_t off = 0;
    auto alloc = [&](size_t bytes) -> void* {
        void* p = ws + off;
        off += (bytes + 255) & ~(size_t)255;
        return p;
    };
    // zero-initialized region must be first & contiguous (ws is poisoned 0xAA each call)
    int*   ideg   = (int*)alloc((size_t)N * 4);
    int*   cursor = (int*)alloc((size_t)N * 4);
    float* fpsum  = (float*)alloc((size_t)N_GRAPHS * HID * 4);
    size_t zero_bytes = off;
    int*   gcnt  = (int*)alloc((size_t)N_GRAPHS * 4);
    float* dis   = (float*)alloc((size_t)N * 4);
    int*   rowst = (int*)alloc((size_t)(N + 1) * 4);
    int*   col   = (int*)alloc((size_t)E * 4);
    int*   goff  = (int*)alloc((size_t)N_GRAPHS * 4);
    int*   bsum  = (int*)alloc((size_t)SCAN_BLK * 4);
    int*   boff  = (int*)alloc((size_t)(SCAN_BLK + 1) * 4);
    float* bufA  = (float*)alloc((size_t)N * HID * 4);
    float* bufB  = (float*)alloc((size_t)N * HID * 4);
    float4* xs   = (float4*)alloc((size_t)N * 16);
    float*  aggx = (float*)alloc((size_t)N * 16);

    hipMemsetAsync(d_ws, 0, zero_bytes, stream);

    const int tpb = 256;
    k_deg<<<(E + tpb - 1) / tpb, tpb, 0, stream>>>(dstp, ideg, E);
    k_scan_part<<<SCAN_BLK, 256, 0, stream>>>(ideg, bsum, dis, x, xs, N);
    k_scan_bsum<<<1, 256, 0, stream>>>(bsum, boff, SCAN_BLK);
    k_scan_write<<<SCAN_BLK, 256, 0, stream>>>(ideg, boff, rowst, N, SCAN_BLK);
    k_fill<<<(E + tpb - 1) / tpb, tpb, 0, stream>>>(srcp, dstp, rowst, cursor, col, E);
    k_goff<<<1, 256, 0, stream>>>(batch, goff, gcnt, N);

    // layer 1: aggregate in 3-dim space, then GEMM (S(xW) = (Sx)W)
    k_agg3<<<(N + 63) / 64, 256, 0, stream>>>(xs, dis, rowst, col, aggx);
    k_gemm_l1<<<(N * 32 + tpb - 1) / tpb, tpb, 0, stream>>>((const float4*)aggx, W1, b1, bufB, N);
    // layer 2
    k_gemm128<<<(N + 127) / 128, 512, 0, stream>>>(bufB, W2, dis, bufA, N);
    k_agg<<<(N + 3) / 4, 256, 0, stream>>>(bufA, dis, rowst, col, b2, bufB);
    // layer 3
    k_gemm128<<<(N + 127) / 128, 512, 0, stream>>>(bufB, W3, dis, bufA, N);
    k_agg<<<(N + 3) / 4, 256, 0, stream>>>(bufA, dis, rowst, col, b3, bufB);
    // pool + classifier
    k_psum<<<(N + POOL_CHUNK - 1) / POOL_CHUNK, HID, 0, stream>>>(bufB, batch, fpsum, N);
    k_final<<<(N_GRAPHS * N_CLASSES + tpb - 1) / tpb, tpb, 0, stream>>>(fpsum, gcnt, Wl, bl, out);
}

// Round 8
// 373.652 us; speedup vs baseline: 7.0848x; 1.1422x over previous
//
#include <hip/hip_runtime.h>

#define N_NODES   50000
#define N_EDGES   600000
#define HID       128
#define N_GRAPHS  128
#define N_CLASSES 5
#define POOL_CHUNK 128
#define SCAN_BLK  ((N_NODES + 255) / 256)   // 196

// --- degree (in-degree by dst, excluding self-loops) ---
__global__ void k_deg(const int* __restrict__ dst, int* __restrict__ ideg, int E) {
    int i = blockIdx.x * blockDim.x + threadIdx.x;
    if (i < E) atomicAdd(&ideg[dst[i]], 1);
}

// --- 3-phase hierarchical scan of ideg -> row_start[0..n] ---
// phase 1 also computes dis[i] = 1/sqrt(deg+1) and xs[i] = dis[i]*x[i] (float4, .w=0)
__global__ void k_scan_part(const int* __restrict__ ideg, int* __restrict__ bsum,
                            float* __restrict__ dis, const float* __restrict__ x,
                            float4* __restrict__ xs, int n) {
    __shared__ int s[256];
    int t = threadIdx.x;
    int i = blockIdx.x * 256 + t;
    int v = (i < n) ? ideg[i] : 0;
    if (i < n) {
        float dd = 1.0f / sqrtf((float)v + 1.0f);
        dis[i] = dd;
        float4 o;
        o.x = dd * x[i * 3 + 0];
        o.y = dd * x[i * 3 + 1];
        o.z = dd * x[i * 3 + 2];
        o.w = 0.f;
        xs[i] = o;
    }
    s[t] = v;
    __syncthreads();
    for (int off = 128; off > 0; off >>= 1) {
        if (t < off) s[t] += s[t + off];
        __syncthreads();
    }
    if (t == 0) bsum[blockIdx.x] = s[0];
}

__global__ void k_scan_bsum(const int* __restrict__ bsum, int* __restrict__ boff, int B) {
    __shared__ int s[256];
    int t = threadIdx.x;
    int v = (t < B) ? bsum[t] : 0;
    s[t] = v;
    __syncthreads();
    for (int off = 1; off < 256; off <<= 1) {
        int u = (t >= off) ? s[t - off] : 0;
        __syncthreads();
        s[t] += u;
        __syncthreads();
    }
    if (t < B) boff[t] = s[t] - v;
    if (t == 255) boff[B] = s[255];  // grand total
}

__global__ void k_scan_write(const int* __restrict__ ideg, const int* __restrict__ boff,
                             int* __restrict__ row_start, int n, int B) {
    __shared__ int s[256];
    int t = threadIdx.x;
    int i = blockIdx.x * 256 + t;
    int v = (i < n) ? ideg[i] : 0;
    s[t] = v;
    __syncthreads();
    for (int off = 1; off < 256; off <<= 1) {
        int u = (t >= off) ? s[t - off] : 0;
        __syncthreads();
        s[t] += u;
        __syncthreads();
    }
    if (i < n) row_start[i] = boff[blockIdx.x] + s[t] - v;
    if (blockIdx.x == 0 && t == 0) row_start[n] = boff[B];
}

// --- CSR fill: col[] holds src of each incoming edge, grouped by dst ---
__global__ void k_fill(const int* __restrict__ src, const int* __restrict__ dst,
                       const int* __restrict__ row_start, int* __restrict__ cursor,
                       int* __restrict__ col, int E) {
    int i = blockIdx.x * blockDim.x + threadIdx.x;
    if (i < E) {
        int d = dst[i];
        int pos = atomicAdd(&cursor[d], 1);
        col[row_start[d] + pos] = src[i];
    }
}

// --- graph offsets via binary search on sorted batch ---
__global__ void k_goff(const int* __restrict__ batch, int* __restrict__ goff,
                       int* __restrict__ gcnt, int n) {
    __shared__ int s[N_GRAPHS + 1];
    int t = threadIdx.x;
    if (t <= N_GRAPHS) {
        int lo = 0, hi = n;
        while (lo < hi) {
            int mid = (lo + hi) >> 1;
            if (batch[mid] < t) lo = mid + 1; else hi = mid;
        }
        s[t] = lo;
        if (t < N_GRAPHS) goff[t] = lo;
    }
    __syncthreads();
    if (t < N_GRAPHS) gcnt[t] = s[t + 1] - s[t];
}

// --- layer-1 aggregation in 3-dim feature space: a[d] = dis_d*(xs[d] + sum_{s in N(d)} xs[s])
// S(xW) = (Sx)W: aggregate first in 3-dim space (800 KB L2-resident table).
__global__ __launch_bounds__(256) void k_agg3(const float4* __restrict__ xs,
                                              const float* __restrict__ dis,
                                              const int* __restrict__ row_start,
                                              const int* __restrict__ col,
                                              float* __restrict__ a) {
    int g = threadIdx.x >> 2;      // 64 dst-groups per block
    int f = threadIdx.x & 3;       // feature component (3 = pad)
    int d = blockIdx.x * 64 + g;
    if (d >= N_NODES) return;
    const float* xsf = (const float*)xs;
    int j0 = row_start[d], j1 = row_start[d + 1];
    float a0 = xsf[(size_t)d * 4 + f];   // self (lane 3 reads the 0 pad)
    float a1 = 0.f, a2 = 0.f, a3 = 0.f;
    int j = j0;
    for (; j + 3 < j1; j += 4) {
        int s0 = col[j], s1 = col[j + 1], s2 = col[j + 2], s3 = col[j + 3];
        a0 += xsf[(size_t)s0 * 4 + f];
        a1 += xsf[(size_t)s1 * 4 + f];
        a2 += xsf[(size_t)s2 * 4 + f];
        a3 += xsf[(size_t)s3 * 4 + f];
    }
    for (; j < j1; ++j)
        a0 += xsf[(size_t)col[j] * 4 + f];
    a[(size_t)d * 4 + f] = dis[d] * ((a0 + a1) + (a2 + a3));
}

// --- layer-1 GEMM on aggregated 3-dim input: h1[i,:] = relu( (a@W1)[i,:] + b1 ) ---
__global__ void k_gemm_l1(const float4* __restrict__ a, const float* __restrict__ W,
                          const float* __restrict__ bias, float* __restrict__ out, int n) {
    int idx = blockIdx.x * blockDim.x + threadIdx.x;  // n*32 threads, 4 cols each
    if (idx >= n * 32) return;
    int row = idx >> 5, c4 = (idx & 31) * 4;
    float4 av = a[row];
    float4 w0 = *(const float4*)&W[0 * HID + c4];
    float4 w1 = *(const float4*)&W[1 * HID + c4];
    float4 w2 = *(const float4*)&W[2 * HID + c4];
    float4 bv = *(const float4*)&bias[c4];
    float4 o;
    o.x = fmaxf(fmaf(av.z, w2.x, fmaf(av.y, w1.x, fmaf(av.x, w0.x, bv.x))), 0.f);
    o.y = fmaxf(fmaf(av.z, w2.y, fmaf(av.y, w1.y, fmaf(av.x, w0.y, bv.y))), 0.f);
    o.z = fmaxf(fmaf(av.z, w2.z, fmaf(av.y, w1.z, fmaf(av.x, w0.z, bv.z))), 0.f);
    o.w = fmaxf(fmaf(av.z, w2.w, fmaf(av.y, w1.w, fmaf(av.x, w0.w, bv.w))), 0.f);
    *(float4*)&out[(size_t)row * HID + c4] = o;
}

// --- 128-row GEMM: out = dis[:,None] * (h @ W).
// 512 threads/block, 128 rows/block, micro-tile 8 rows x 4 cols per thread.
// Full 128x128 W (64 KB) in LDS (staged once) + h k-slices via a
// double-buffered 128x8 LDS tile (2 x 4 KB), T14 issue-early/write-late.
// LAUNCH BOUNDS (round-6 lesson): HIP 2nd arg = min BLOCKS per CU (CUDA
// semantics). (512,4) forced 32 waves/CU -> 64-VGPR cap -> acc spilled to
// scratch (WRITE_SIZE 80 MB vs 25 MB output, 69 us). (512,2) -> 128-VGPR
// cap >= ~100 needed; LDS (72 KB) already limits to 2 blocks/CU anyway.
__global__ __launch_bounds__(512, 2) void k_gemm128(const float* __restrict__ h,
                                                    const float* __restrict__ W,
                                                    const float* __restrict__ dis,
                                                    float* __restrict__ out, int n) {
    __shared__ float Ws[HID * HID];      // 64 KB
    __shared__ float Hs[2][128 * 8];     // 2 x 4 KB
    int t  = threadIdx.x;
    int tc = t & 31;        // col group: cols 4*tc .. 4*tc+3
    int tr = t >> 5;        // row group 0..15: rows row0 .. row0+7
    int row0 = blockIdx.x * 128 + tr * 8;

    // stage all of W: 8 coalesced 512-thread stripes of float4
    {
        const float4* wg = (const float4*)W;
        float4* wsv = (float4*)Ws;
#pragma unroll
        for (int i = 0; i < 8; ++i)
            wsv[i * 512 + t] = wg[i * 512 + t];
    }

    // h staging: threads 0..255 stage 128 rows x 8 k per step (row = t>>1, half = t&1)
    int srow = blockIdx.x * 128 + (t >> 1);
    if (srow >= n) srow = n - 1;                 // clamp; stores guarded below
    const float* hsrc = h + (size_t)srow * HID + (t & 1) * 4;
    int sidx = (t >> 1) * 8 + (t & 1) * 4;
    if (t < 256)
        *(float4*)&Hs[0][sidx] = *(const float4*)hsrc;

    float acc[8][4];
#pragma unroll
    for (int r = 0; r < 8; ++r)
#pragma unroll
        for (int c = 0; c < 4; ++c) acc[r][c] = 0.f;

    __syncthreads();

    int buf = 0;
    for (int k0 = 0; k0 < HID; k0 += 8) {       // NOT unrolled (VGPR discipline)
        // T14 issue-early: next k-slice global->reg
        float4 pf;
        bool do_pf = (k0 + 8 < HID) && (t < 256);
        if (do_pf) pf = *(const float4*)(hsrc + k0 + 8);

        // h fragment for this step: 8 rows x 8 k from LDS (broadcast reads)
        float4 hv4[8];
#pragma unroll
        for (int r = 0; r < 8; ++r)
            hv4[r] = *(const float4*)&Hs[buf][(tr * 8 + r) * 8];
#pragma unroll
        for (int kk = 0; kk < 4; ++kk) {
            float4 wv = *(const float4*)&Ws[(k0 + kk) * HID + tc * 4];
#pragma unroll
            for (int r = 0; r < 8; ++r) {
                float hv = kk == 0 ? hv4[r].x : kk == 1 ? hv4[r].y : kk == 2 ? hv4[r].z : hv4[r].w;
                acc[r][0] = fmaf(hv, wv.x, acc[r][0]);
                acc[r][1] = fmaf(hv, wv.y, acc[r][1]);
                acc[r][2] = fmaf(hv, wv.z, acc[r][2]);
                acc[r][3] = fmaf(hv, wv.w, acc[r][3]);
            }
        }
#pragma unroll
        for (int r = 0; r < 8; ++r)
            hv4[r] = *(const float4*)&Hs[buf][(tr * 8 + r) * 8 + 4];
#pragma unroll
        for (int kk = 0; kk < 4; ++kk) {
            float4 wv = *(const float4*)&Ws[(k0 + 4 + kk) * HID + tc * 4];
#pragma unroll
            for (int r = 0; r < 8; ++r) {
                float hv = kk == 0 ? hv4[r].x : kk == 1 ? hv4[r].y : kk == 2 ? hv4[r].z : hv4[r].w;
                acc[r][0] = fmaf(hv, wv.x, acc[r][0]);
                acc[r][1] = fmaf(hv, wv.y, acc[r][1]);
                acc[r][2] = fmaf(hv, wv.z, acc[r][2]);
                acc[r][3] = fmaf(hv, wv.w, acc[r][3]);
            }
        }

        // T14 write-late: latency hidden under the FMAs above
        if (do_pf) *(float4*)&Hs[buf ^ 1][sidx] = pf;
        __syncthreads();
        buf ^= 1;
    }

#pragma unroll
    for (int r = 0; r < 8; ++r) {
        int row = row0 + r;
        if (row < n) {
            float dd = dis[row];
            float4 o;
            o.x = dd * acc[r][0]; o.y = dd * acc[r][1];
            o.z = dd * acc[r][2]; o.w = dd * acc[r][3];
            *(float4*)&out[(size_t)row * HID + tc * 4] = o;
        }
    }
}

// --- aggregation on pre-scaled t: out[d] = relu( dis[d] * (t[d] + sum_{s in N(d)} t[s]) + b )
__global__ __launch_bounds__(256) void k_agg(const float* __restrict__ t,
                                             const float* __restrict__ dis,
                                             const int* __restrict__ row_start,
                                             const int* __restrict__ col,
                                             const float* __restrict__ bias,
                                             float* __restrict__ out) {
    int lane = threadIdx.x & 63;
    int wid  = threadIdx.x >> 6;
    int d = blockIdx.x * 4 + wid;
    if (d >= N_NODES) return;
    const float2* t2 = (const float2*)t;
    float2 bv = ((const float2*)bias)[lane];
    float dd = dis[d];
    int j0 = row_start[d], j1 = row_start[d + 1];
    float2 self = t2[(size_t)d * 64 + lane];
    float ax0 = self.x, ay0 = self.y;
    float ax1 = 0.f, ay1 = 0.f, ax2 = 0.f, ay2 = 0.f, ax3 = 0.f, ay3 = 0.f;
    int j = j0;
    for (; j + 3 < j1; j += 4) {
        int s0 = col[j], s1 = col[j + 1], s2 = col[j + 2], s3 = col[j + 3];
        float2 v0 = t2[(size_t)s0 * 64 + lane];
        float2 v1 = t2[(size_t)s1 * 64 + lane];
        float2 v2 = t2[(size_t)s2 * 64 + lane];
        float2 v3 = t2[(size_t)s3 * 64 + lane];
        ax0 += v0.x; ay0 += v0.y;
        ax1 += v1.x; ay1 += v1.y;
        ax2 += v2.x; ay2 += v2.y;
        ax3 += v3.x; ay3 += v3.y;
    }
    for (; j < j1; ++j) {
        int s = col[j];
        float2 v = t2[(size_t)s * 64 + lane];
        ax0 += v.x; ay0 += v.y;
    }
    float sx = (ax0 + ax1) + (ax2 + ax3);
    float sy = (ay0 + ay1) + (ay2 + ay3);
    float2 o;
    o.x = fmaxf(fmaf(dd, sx, bv.x), 0.f);
    o.y = fmaxf(fmaf(dd, sy, bv.y), 0.f);
    ((float2*)out)[(size_t)d * 64 + lane] = o;
}

// --- node-parallel pool partial sums ---
__global__ void k_psum(const float* __restrict__ h, const int* __restrict__ batch,
                       float* __restrict__ fpsum, int n) {
    int i0 = blockIdx.x * POOL_CHUNK;
    int f = threadIdx.x;
    int end = min(i0 + POOL_CHUNK, n);
    int cur = batch[i0];
    float acc = 0.f;
    for (int i = i0; i < end; ++i) {
        int g = batch[i];
        if (g != cur) {
            atomicAdd(&fpsum[cur * HID + f], acc);
            acc = 0.f;
            cur = g;
        }
        acc += h[(size_t)i * HID + f];
    }
    atomicAdd(&fpsum[cur * HID + f], acc);
}

// --- final linear with mean folded in ---
__global__ void k_final(const float* __restrict__ fpsum, const int* __restrict__ gcnt,
                        const float* __restrict__ Wl, const float* __restrict__ bl,
                        float* __restrict__ out) {
    int idx = blockIdx.x * blockDim.x + threadIdx.x;
    if (idx >= N_GRAPHS * N_CLASSES) return;
    int g = idx / N_CLASSES, c = idx % N_CLASSES;
    float inv = 1.0f / (float)max(gcnt[g], 1);
    float acc = bl[c];
    for (int f = 0; f < HID; ++f)
        acc = fmaf(fpsum[g * HID + f] * inv, Wl[f * N_CLASSES + c], acc);
    out[idx] = acc;
}

extern "C" void kernel_launch(void* const* d_in, const int* in_sizes, int n_in,
                              void* d_out, int out_size, void* d_ws, size_t ws_size,
                              hipStream_t stream) {
    const float* x     = (const float*)d_in[0];
    const int*   ei    = (const int*)d_in[1];   // [2, E]: row0 = src, row1 = dst
    const int*   batch = (const int*)d_in[2];
    const float* W1 = (const float*)d_in[3];
    const float* b1 = (const float*)d_in[4];
    const float* W2 = (const float*)d_in[5];
    const float* b2 = (const float*)d_in[6];
    const float* W3 = (const float*)d_in[7];
    const float* b3 = (const float*)d_in[8];
    const float* Wl = (const float*)d_in[9];
    const float* bl = (const float*)d_in[10];
    float* out = (float*)d_out;

    const int N = N_NODES, E = N_EDGES;
    const int* srcp = ei;
    const int* dstp = ei + E;

    char* ws = (char*)d_ws;
    size_t off = 0;
    auto alloc = [&](size_t bytes) -> void* {
        void* p = ws + off;
        off += (bytes + 255) & ~(size_t)255;
        return p;
    };
    // zero-initialized region must be first & contiguous (ws is poisoned 0xAA each call)
    int*   ideg   = (int*)alloc((size_t)N * 4);
    int*   cursor = (int*)alloc((size_t)N * 4);
    float* fpsum  = (float*)alloc((size_t)N_GRAPHS * HID * 4);
    size_t zero_bytes = off;
    int*   gcnt  = (int*)alloc((size_t)N_GRAPHS * 4);
    float* dis   = (float*)alloc((size_t)N * 4);
    int*   rowst = (int*)alloc((size_t)(N + 1) * 4);
    int*   col   = (int*)alloc((size_t)E * 4);
    int*   goff  = (int*)alloc((size_t)N_GRAPHS * 4);
    int*   bsum  = (int*)alloc((size_t)SCAN_BLK * 4);
    int*   boff  = (int*)alloc((size_t)(SCAN_BLK + 1) * 4);
    float* bufA  = (float*)alloc((size_t)N * HID * 4);
    float* bufB  = (float*)alloc((size_t)N * HID * 4);
    float4* xs   = (float4*)alloc((size_t)N * 16);
    float*  aggx = (float*)alloc((size_t)N * 16);

    hipMemsetAsync(d_ws, 0, zero_bytes, stream);

    const int tpb = 256;
    k_deg<<<(E + tpb - 1) / tpb, tpb, 0, stream>>>(dstp, ideg, E);
    k_scan_part<<<SCAN_BLK, 256, 0, stream>>>(ideg, bsum, dis, x, xs, N);
    k_scan_bsum<<<1, 256, 0, stream>>>(bsum, boff, SCAN_BLK);
    k_scan_write<<<SCAN_BLK, 256, 0, stream>>>(ideg, boff, rowst, N, SCAN_BLK);
    k_fill<<<(E + tpb - 1) / tpb, tpb, 0, stream>>>(srcp, dstp, rowst, cursor, col, E);
    k_goff<<<1, 256, 0, stream>>>(batch, goff, gcnt, N);

    // layer 1: aggregate in 3-dim space, then GEMM (S(xW) = (Sx)W)
    k_agg3<<<(N + 63) / 64, 256, 0, stream>>>(xs, dis, rowst, col, aggx);
    k_gemm_l1<<<(N * 32 + tpb - 1) / tpb, tpb, 0, stream>>>((const float4*)aggx, W1, b1, bufB, N);
    // layer 2
    k_gemm128<<<(N + 127) / 128, 512, 0, stream>>>(bufB, W2, dis, bufA, N);
    k_agg<<<(N + 3) / 4, 256, 0, stream>>>(bufA, dis, rowst, col, b2, bufB);
    // layer 3
    k_gemm128<<<(N + 127) / 128, 512, 0, stream>>>(bufB, W3, dis, bufA, N);
    k_agg<<<(N + 3) / 4, 256, 0, stream>>>(bufA, dis, rowst, col, b3, bufB);
    // pool + classifier
    k_psum<<<(N + POOL_CHUNK - 1) / POOL_CHUNK, HID, 0, stream>>>(bufB, batch, fpsum, N);
    k_final<<<(N_GRAPHS * N_CLASSES + tpb - 1) / tpb, tpb, 0, stream>>>(fpsum, gcnt, Wl, bl, out);
}